// Round 17
// baseline (129.203 us; speedup 1.0000x reference)
//
#include <hip/hip_runtime.h>
#include <hip/hip_bf16.h>
#include <cstdint>
#include <cstddef>

static constexpr int NN = 100000;   // nodes
static constexpr int NE = 1600000;  // edges
static constexpr int NB = 391;      // buckets of 256 rows
static constexpr int GB = 250;      // blocks in hist/bucket passes (250*6400 == NE)
static constexpr int CHUNK = NE / GB;             // 6400 (int4-aligned chunks)

typedef __attribute__((ext_vector_type(8))) short bf16x8;
typedef __attribute__((ext_vector_type(4))) float f32x4;

static __device__ __forceinline__ unsigned short f2bf(float f) {
  unsigned u = __float_as_uint(f);
  unsigned r = (u + 0x7fffu + ((u >> 16) & 1u)) >> 16;  // RNE
  return (unsigned short)r;
}

// ---------------- pass A: per-(bucket,block) histogram (int4 reads) ----------------

__global__ __launch_bounds__(256) void k_hist(const int* __restrict__ row,
                                              int* __restrict__ counts) {
  __shared__ int hist[NB];
  for (int k = threadIdx.x; k < NB; k += 256) hist[k] = 0;
  __syncthreads();
  int g = blockIdx.x;
  int start = g * CHUNK;
  for (int gi = threadIdx.x; gi < CHUNK / 4; gi += 256) {
    int4 r4 = *reinterpret_cast<const int4*>(row + start + gi * 4);
    atomicAdd(&hist[r4.x >> 8], 1);
    atomicAdd(&hist[r4.y >> 8], 1);
    atomicAdd(&hist[r4.z >> 8], 1);
    atomicAdd(&hist[r4.w >> 8], 1);
  }
  __syncthreads();
  for (int k = threadIdx.x; k < NB; k += 256) counts[k * GB + g] = hist[k];
}

// ---------------- scan A: per-bucket exclusive scan of 250 block-counts ----------------

__global__ __launch_bounds__(256) void k_scanA(int* __restrict__ counts,
                                               int* __restrict__ totals) {
  __shared__ int s[256];
  int k = blockIdx.x;
  int i = threadIdx.x;
  int v = (i < GB) ? counts[k * GB + i] : 0;
  s[i] = v;
  __syncthreads();
  for (int off = 1; off < 256; off <<= 1) {
    int t = (i >= off) ? s[i - off] : 0;
    __syncthreads();
    s[i] += t;
    __syncthreads();
  }
  if (i < GB) counts[k * GB + i] = s[i] - v;
  if (i == 255) totals[k] = s[255];
}

// ---------------- inline totals->bases scan (LDS), shared by bucket/csr ----------------

static __device__ __forceinline__ void scan_totals(const int* __restrict__ totals,
                                                   int* bases_l, int* ss,
                                                   int* carry_p) {
  if (threadIdx.x == 0) *carry_p = 0;
  __syncthreads();
  for (int base = 0; base < NB; base += 256) {
    int i = base + threadIdx.x;
    int v = (i < NB) ? totals[i] : 0;
    ss[threadIdx.x] = v;
    __syncthreads();
    for (int off = 1; off < 256; off <<= 1) {
      int t = (threadIdx.x >= off) ? ss[threadIdx.x - off] : 0;
      __syncthreads();
      ss[threadIdx.x] += t;
      __syncthreads();
    }
    if (i < NB) bases_l[i] = *carry_p + ss[threadIdx.x] - v;
    int tile_total = ss[255];
    __syncthreads();
    if (threadIdx.x == 0) *carry_p += tile_total;
    __syncthreads();
  }
  if (threadIdx.x == 0) bases_l[NB] = *carry_p;
  __syncthreads();
}

// ---------------- pass B: bucket-grouped packed edges (int4 reads) ----------------

__global__ __launch_bounds__(256) void k_bucket(const int* __restrict__ row,
                                                const int* __restrict__ col,
                                                const int* __restrict__ counts,
                                                const int* __restrict__ totals,
                                                unsigned int* __restrict__ packed) {
  __shared__ int cur[NB];
  __shared__ int bases_l[NB + 1];
  __shared__ int ss[256];
  __shared__ int carry;
  scan_totals(totals, bases_l, ss, &carry);

  int g = blockIdx.x;
  for (int k = threadIdx.x; k < NB; k += 256)
    cur[k] = bases_l[k] + counts[k * GB + g];
  __syncthreads();
  int start = g * CHUNK;
  for (int gi = threadIdx.x; gi < CHUNK / 4; gi += 256) {
    int4 r4 = *reinterpret_cast<const int4*>(row + start + gi * 4);
    int4 c4 = *reinterpret_cast<const int4*>(col + start + gi * 4);
    int p0 = atomicAdd(&cur[r4.x >> 8], 1);
    int p1 = atomicAdd(&cur[r4.y >> 8], 1);
    int p2 = atomicAdd(&cur[r4.z >> 8], 1);
    int p3 = atomicAdd(&cur[r4.w >> 8], 1);
    packed[p0] = ((unsigned)(r4.x & 255) << 17) | (unsigned)c4.x;
    packed[p1] = ((unsigned)(r4.y & 255) << 17) | (unsigned)c4.y;
    packed[p2] = ((unsigned)(r4.z & 255) << 17) | (unsigned)c4.z;
    packed[p3] = ((unsigned)(r4.w & 255) << 17) | (unsigned)c4.w;
  }
}

// ---------------- pass C: per-bucket CSR finalize (arrival order) + fused x-cast ----

__global__ __launch_bounds__(256) void k_csr(const unsigned int* __restrict__ packed,
                                             const int* __restrict__ totals,
                                             int* __restrict__ rowptr,
                                             float* __restrict__ dis,
                                             int* __restrict__ csr_col,
                                             const float* __restrict__ x,
                                             unsigned short* __restrict__ xb,
                                             int N, int E) {
  __shared__ int bases_l[NB + 1];
  __shared__ int ss[256];
  __shared__ int carry;
  __shared__ int rh[256];
  __shared__ int cur[256];
  __shared__ float ldis[256];
  scan_totals(totals, bases_l, ss, &carry);

  int b = blockIdx.x;
  int start = bases_l[b];
  int end = bases_l[b + 1];

  rh[threadIdx.x] = 0;
  __syncthreads();
  for (int i = start + threadIdx.x; i < end; i += 256)
    atomicAdd(&rh[packed[i] >> 17], 1);
  __syncthreads();

  int v = rh[threadIdx.x];
  ss[threadIdx.x] = v;
  __syncthreads();
  for (int off = 1; off < 256; off <<= 1) {
    int t = (threadIdx.x >= off) ? ss[threadIdx.x - off] : 0;
    __syncthreads();
    ss[threadIdx.x] += t;
    __syncthreads();
  }
  int exc = ss[threadIdx.x] - v;

  float dv = 1.0f / sqrtf((float)v + 1e-12f);
  ldis[threadIdx.x] = dv;
  int gr = (b << 8) + threadIdx.x;
  if (gr < N) {
    rowptr[gr] = start + exc;
    dis[gr] = dv;
  }
  if (b == NB - 1 && threadIdx.x == 0) rowptr[N] = E;

  cur[threadIdx.x] = exc;
  __syncthreads();
  for (int i = start + threadIdx.x; i < end; i += 256) {
    unsigned p = packed[i];
    int lr = p >> 17;
    int c = (int)(p & 0x1FFFFu);
    int pos = atomicAdd(&cur[lr], 1);
    csr_col[start + pos] = c;
  }

  // fused cast: this bucket's rows of x -> bf16 * dis (coalesced float4 loop)
  int rows = min(256, N - (b << 8));
  if (rows > 0) {
    const float4* xs = reinterpret_cast<const float4*>(x + ((size_t)b << 8) * 32);
    ushort4* xd = reinterpret_cast<ushort4*>(xb + ((size_t)b << 8) * 32);
    for (int i = threadIdx.x; i < rows * 8; i += 256) {
      float ds = ldis[i >> 3];
      float4 vv = xs[i];
      xd[i] = make_ushort4(f2bf(vv.x * ds), f2bf(vv.y * ds),
                           f2bf(vv.z * ds), f2bf(vv.w * ds));
    }
  }
}

// ---------------- bf16 accumulate helper ----------------

template <int SQ>
static __device__ __forceinline__ void acc_bf(float* acc, const uint4* u) {
#pragma unroll
  for (int q = 0; q < SQ; ++q) {
    acc[8 * q + 0] += __uint_as_float(u[q].x << 16);
    acc[8 * q + 1] += __uint_as_float(u[q].x & 0xffff0000u);
    acc[8 * q + 2] += __uint_as_float(u[q].y << 16);
    acc[8 * q + 3] += __uint_as_float(u[q].y & 0xffff0000u);
    acc[8 * q + 4] += __uint_as_float(u[q].z << 16);
    acc[8 * q + 5] += __uint_as_float(u[q].z & 0xffff0000u);
    acc[8 * q + 6] += __uint_as_float(u[q].w << 16);
    acc[8 * q + 7] += __uint_as_float(u[q].w & 0xffff0000u);
  }
}

// ---------------- FUSED layer-1 gather + MFMA double GEMM ----------------
// Block = 64 rows. Phase 1: 4 lanes/row gather xb -> bf16 tile in LDS.
// Phase 2: per-wave 16-row MFMA gemm12 reading B-fragments from the LDS tile.
// s2 rows are 48 bf16 = 96 B (UNPADDED: shrinks layer-2 gather footprint
// 12.8->9.6 MB -> fetch floor 102->77 MB). Epilogue write is linear in
// uint4 index (rb*6+q) -> fully coalesced.

__global__ __launch_bounds__(256) void k_g1gemm(
    const uint4* __restrict__ src,            // xb rows = 4 uint4
    const int* __restrict__ rowptr,
    const int* __restrict__ csr_col,
    const float* __restrict__ dis,
    const float* __restrict__ W1,             // [32][48]
    const float* __restrict__ W2,             // [48][48]
    unsigned short* __restrict__ s2,          // [N][48] bf16 (96B rows)
    int N) {
  __shared__ __align__(16) unsigned short g1l[64][36];
  __shared__ __align__(16) unsigned short hl[4][16][72];

  int rb0 = blockIdx.x * 64;

  // ---- phase 1: gather this block's 64 rows ----
  {
    int lr = threadIdx.x >> 2, gg = threadIdx.x & 3;
    int r = rb0 + lr;
    uint4 pk = make_uint4(0u, 0u, 0u, 0u);
    if (r < N) {
      int j = rowptr[r], end = rowptr[r + 1];
      float acc[8];
#pragma unroll
      for (int q = 0; q < 8; ++q) acc[q] = 0.f;
      for (; j + 4 <= end; j += 4) {
        int c0 = csr_col[j], c1 = csr_col[j + 1];
        int c2 = csr_col[j + 2], c3 = csr_col[j + 3];
        uint4 u0 = src[(size_t)c0 * 4 + gg];
        uint4 u1 = src[(size_t)c1 * 4 + gg];
        uint4 u2 = src[(size_t)c2 * 4 + gg];
        uint4 u3 = src[(size_t)c3 * 4 + gg];
        acc_bf<1>(acc, &u0);
        acc_bf<1>(acc, &u1);
        acc_bf<1>(acc, &u2);
        acc_bf<1>(acc, &u3);
      }
      for (; j < end; ++j) {
        uint4 u0 = src[(size_t)csr_col[j] * 4 + gg];
        acc_bf<1>(acc, &u0);
      }
      float ds = dis[r];
      unsigned* pw = reinterpret_cast<unsigned*>(&pk);
#pragma unroll
      for (int i = 0; i < 4; ++i)
        pw[i] = (unsigned)f2bf(ds * acc[2 * i]) |
                ((unsigned)f2bf(ds * acc[2 * i + 1]) << 16);
    }
    *reinterpret_cast<uint4*>(&g1l[lr][gg * 8]) = pk;
  }
  __syncthreads();

  // ---- phase 2: MFMA gemm12 ----
  int w = threadIdx.x >> 6;   // wave id
  int l = threadIdx.x & 63;
  int c = l & 15;             // node-row slot within tile (MFMA col)
  int g = l >> 4;             // k-group
  int rb = rb0 + w * 16;
  int r = rb + c;
  int rc = min(r, N - 1);

  bf16x8 w1f[3];
#pragma unroll
  for (int t = 0; t < 3; ++t) {
#pragma unroll
    for (int i = 0; i < 8; ++i)
      w1f[t][i] = (short)f2bf(W1[(g * 8 + i) * 48 + 16 * t + c]);
  }
  bf16x8 w2f[3][2];
#pragma unroll
  for (int t = 0; t < 3; ++t) {
#pragma unroll
    for (int s = 0; s < 2; ++s) {
#pragma unroll
      for (int i = 0; i < 8; ++i) {
        int k = s * 32 + g * 8 + i;
        w2f[t][s][i] = (k < 48) ? (short)f2bf(W2[k * 48 + 16 * t + c]) : (short)0;
      }
    }
  }

  bf16x8 bfr = *reinterpret_cast<const bf16x8*>(&g1l[w * 16 + c][g * 8]);
  f32x4 a1[3];
#pragma unroll
  for (int t = 0; t < 3; ++t) {
    a1[t] = f32x4{0.f, 0.f, 0.f, 0.f};
    a1[t] = __builtin_amdgcn_mfma_f32_16x16x32_bf16(w1f[t], bfr, a1[t], 0, 0, 0);
  }

#pragma unroll
  for (int t = 0; t < 3; ++t) {
    int f = 16 * t + 4 * g;
    unsigned p0 = (unsigned)f2bf(fmaxf(a1[t][0], 0.f)) |
                  ((unsigned)f2bf(fmaxf(a1[t][1], 0.f)) << 16);
    unsigned p1 = (unsigned)f2bf(fmaxf(a1[t][2], 0.f)) |
                  ((unsigned)f2bf(fmaxf(a1[t][3], 0.f)) << 16);
    *reinterpret_cast<unsigned*>(&hl[w][c][f]) = p0;
    *reinterpret_cast<unsigned*>(&hl[w][c][f + 2]) = p1;
  }
  // zero feats 48..63 (K-pad read by GEMM2's s=1 B-fragments; avoids NaN*0)
  *reinterpret_cast<unsigned*>(&hl[w][c][48 + 4 * g]) = 0u;
  *reinterpret_cast<unsigned*>(&hl[w][c][48 + 4 * g + 2]) = 0u;

  f32x4 a2[3];
#pragma unroll
  for (int t = 0; t < 3; ++t) a2[t] = f32x4{0.f, 0.f, 0.f, 0.f};
#pragma unroll
  for (int s = 0; s < 2; ++s) {
    bf16x8 hb = *reinterpret_cast<const bf16x8*>(&hl[w][c][s * 32 + 8 * g]);
#pragma unroll
    for (int t = 0; t < 3; ++t)
      a2[t] = __builtin_amdgcn_mfma_f32_16x16x32_bf16(w2f[t][s], hb, a2[t], 0, 0, 0);
  }

  float ds = dis[rc];
#pragma unroll
  for (int t = 0; t < 3; ++t) {
    int f = 16 * t + 4 * g;
    unsigned p0 = (unsigned)f2bf(ds * a2[t][0]) |
                  ((unsigned)f2bf(ds * a2[t][1]) << 16);
    unsigned p1 = (unsigned)f2bf(ds * a2[t][2]) |
                  ((unsigned)f2bf(ds * a2[t][3]) << 16);
    *reinterpret_cast<unsigned*>(&hl[w][c][f]) = p0;
    *reinterpret_cast<unsigned*>(&hl[w][c][f + 2]) = p1;
  }
  // 96B rows: 16 rows x 6 uint4 = 96 chunks; global uint4 idx = rb*6 + q (linear)
#pragma unroll
  for (int h2 = 0; h2 < 2; ++h2) {
    int q = l + 64 * h2;
    if (q < 96) {
      int rowq = q / 6, off = q - rowq * 6;
      int rr = rb + rowq;
      if (rr < N) {
        uint4 v = *reinterpret_cast<const uint4*>(&hl[w][rowq][off * 8]);
        *reinterpret_cast<uint4*>(s2 + (size_t)rr * 48 + off * 8) = v;
      }
    }
  }
}

// ---------------- fused layer-2 gather + layer-3 GEMM (bf16 s3 out) ----------------
// s2 rows = 6 uint4 (96B). 8 lanes/row, lanes g>=6 idle in the gather (v=0).
// Wol stride 68: lane-group g reads bank (4g+c)%32 — conflict-free.

__global__ __launch_bounds__(256) void k_gather_fc(const uint4* __restrict__ src,
                                                   const int* __restrict__ rowptr,
                                                   const int* __restrict__ csr_col,
                                                   const float* __restrict__ dis,
                                                   const float* __restrict__ Wo,
                                                   unsigned short* __restrict__ s3b,
                                                   int N) {
  __shared__ float Wol[8 * 68];
  for (int i = threadIdx.x; i < 8 * 68; i += 256) {
    int gg = i / 68, off = i - gg * 68;
    float v = 0.f;
    if (off < 64) {
      int rowf = gg * 8 + (off >> 3);
      if (rowf < 48) v = Wo[rowf * 8 + (off & 7)];
    }
    Wol[i] = v;
  }
  __syncthreads();

  int t = blockIdx.x * 256 + threadIdx.x;
  int r = t >> 3, g = t & 7;
  if (r >= N) return;

  float acc[8];
#pragma unroll
  for (int q = 0; q < 8; ++q) acc[q] = 0.f;

  if (g < 6) {
    int j = rowptr[r], end = rowptr[r + 1];
    for (; j + 4 <= end; j += 4) {
      int c0 = csr_col[j], c1 = csr_col[j + 1];
      int c2 = csr_col[j + 2], c3 = csr_col[j + 3];
      uint4 u0 = src[(size_t)c0 * 6 + g];
      uint4 u1 = src[(size_t)c1 * 6 + g];
      uint4 u2 = src[(size_t)c2 * 6 + g];
      uint4 u3 = src[(size_t)c3 * 6 + g];
      acc_bf<1>(acc, &u0);
      acc_bf<1>(acc, &u1);
      acc_bf<1>(acc, &u2);
      acc_bf<1>(acc, &u3);
    }
    for (; j < end; ++j) {
      uint4 u0 = src[(size_t)csr_col[j] * 6 + g];
      acc_bf<1>(acc, &u0);
    }
  }

  float ds = dis[r];
  float v[8];
#pragma unroll
  for (int q = 0; q < 8; ++q) v[q] = fmaxf(ds * acc[q], 0.f);

  float p[8];
#pragma unroll
  for (int n = 0; n < 8; ++n) p[n] = 0.f;
  const float* wbase = &Wol[g * 68];
#pragma unroll
  for (int q = 0; q < 8; ++q) {
    float4 w0 = *reinterpret_cast<const float4*>(wbase + q * 8);
    float4 w1 = *reinterpret_cast<const float4*>(wbase + q * 8 + 4);
    p[0] = fmaf(v[q], w0.x, p[0]);
    p[1] = fmaf(v[q], w0.y, p[1]);
    p[2] = fmaf(v[q], w0.z, p[2]);
    p[3] = fmaf(v[q], w0.w, p[3]);
    p[4] = fmaf(v[q], w1.x, p[4]);
    p[5] = fmaf(v[q], w1.y, p[5]);
    p[6] = fmaf(v[q], w1.z, p[6]);
    p[7] = fmaf(v[q], w1.w, p[7]);
  }
#pragma unroll
  for (int m = 1; m < 8; m <<= 1) {
#pragma unroll
    for (int n = 0; n < 8; ++n) p[n] += __shfl_xor(p[n], m, 64);
  }
  if (g == 0) {
    uint4 pk;
    unsigned* pw = reinterpret_cast<unsigned*>(&pk);
#pragma unroll
    for (int i = 0; i < 4; ++i)
      pw[i] = (unsigned)f2bf(ds * p[2 * i]) |
              ((unsigned)f2bf(ds * p[2 * i + 1]) << 16);
    *reinterpret_cast<uint4*>(s3b + (size_t)r * 8) = pk;
  }
}

// ---------------- final gather: out[r,:] = dis[r] * sum s3b[col,:] (f32 out) ----------------

__global__ __launch_bounds__(256) void k_gather_s3(const uint4* __restrict__ src,
                                                   const int* __restrict__ rowptr,
                                                   const int* __restrict__ csr_col,
                                                   const float* __restrict__ dis,
                                                   float* __restrict__ out, int N) {
  int r = blockIdx.x * 256 + threadIdx.x;
  if (r >= N) return;
  int j = rowptr[r], end = rowptr[r + 1];

  float acc[8];
#pragma unroll
  for (int q = 0; q < 8; ++q) acc[q] = 0.f;

  for (; j + 4 <= end; j += 4) {
    int c0 = csr_col[j], c1 = csr_col[j + 1], c2 = csr_col[j + 2], c3 = csr_col[j + 3];
    uint4 u0 = src[c0];
    uint4 u1 = src[c1];
    uint4 u2 = src[c2];
    uint4 u3 = src[c3];
    acc_bf<1>(acc, &u0);
    acc_bf<1>(acc, &u1);
    acc_bf<1>(acc, &u2);
    acc_bf<1>(acc, &u3);
  }
  for (; j < end; ++j) {
    uint4 u0 = src[csr_col[j]];
    acc_bf<1>(acc, &u0);
  }

  float ds = dis[r];
  float4* dp = reinterpret_cast<float4*>(out + (size_t)r * 8);
  dp[0] = make_float4(ds * acc[0], ds * acc[1], ds * acc[2], ds * acc[3]);
  dp[1] = make_float4(ds * acc[4], ds * acc[5], ds * acc[6], ds * acc[7]);
}

// ---------------- launch ----------------

extern "C" void kernel_launch(void* const* d_in, const int* in_sizes, int n_in,
                              void* d_out, int out_size, void* d_ws, size_t ws_size,
                              hipStream_t stream) {
  const float* x  = (const float*)d_in[0];
  const int*   ei = (const int*)d_in[1];
  const float* W1 = (const float*)d_in[2];
  const float* W2 = (const float*)d_in[3];
  const float* Wo = (const float*)d_in[4];
  float* out = (float*)d_out;

  const int N = NN, E = NE;
  const int* row = ei;
  const int* col = ei + E;

  // workspace — every buffer on a 128B (32-word) boundary (R15 lesson).
  int*   counts  = (int*)d_ws;                   // 97750 -> pad 97760
  int*   totals  = counts + 97760;               // 391   -> pad 416
  int*   rowptr  = totals + 416;                 // 100001-> pad 100032
  float* dis     = (float*)(rowptr + 100032);    // 100000
  int*   csr_col = (int*)(dis + 100000);         // 1600000
  float* A1      = (float*)(csr_col + NE);       // 2.4M words, 128B-aligned
  unsigned short* xb  = (unsigned short*)(A1 + 2400000);  // N*32 bf16 (1.6M words)
  unsigned short* s3b = (unsigned short*)(A1 + 4000000);  // N*8 bf16 (0.4M words)
  // aliases (lifetimes disjoint):
  unsigned int*   packed = (unsigned int*)A1;    // CSR build only (1.6M words)
  unsigned short* s2     = (unsigned short*)A1;  // N*48 bf16 rows (2.4M words)

  // ---- CSR build (+fused cast); totals->bases scan inlined in consumers ----
  k_hist<<<GB, 256, 0, stream>>>(row, counts);
  k_scanA<<<NB, 256, 0, stream>>>(counts, totals);
  k_bucket<<<GB, 256, 0, stream>>>(row, col, counts, totals, packed);
  k_csr<<<NB, 256, 0, stream>>>(packed, totals, rowptr, dis, csr_col, x, xb, N, E);

  // ---- fused layer-1 gather + MFMA gemm12: s2 = bf16(dis*(relu((Ā@xb)@W1)@W2)) ----
  k_g1gemm<<<(N + 63) / 64, 256, 0, stream>>>(
      (const uint4*)xb, rowptr, csr_col, dis, W1, W2, s2, N);

  // ---- fused layer-2 gather + layer-3 GEMM: s3b = bf16(dis*(relu(dis*(Ā@s2))@Wo)) ----
  k_gather_fc<<<(N * 8 + 255) / 256, 256, 0, stream>>>(
      (const uint4*)s2, rowptr, csr_col, dis, Wo, s3b, N);

  // ---- final gather: out = dis⊙(Ā@s3b) ----
  k_gather_s3<<<(N + 255) / 256, 256, 0, stream>>>(
      (const uint4*)s3b, rowptr, csr_col, dis, out, N);
}

// Round 18
// 128.228 us; speedup vs baseline: 1.0076x; 1.0076x over previous
//
#include <hip/hip_runtime.h>
#include <hip/hip_bf16.h>
#include <cstdint>
#include <cstddef>

static constexpr int NN = 100000;   // nodes
static constexpr int NE = 1600000;  // edges
static constexpr int NB = 391;      // buckets of 256 rows
static constexpr int GB = 500;      // blocks in hist/bucket passes (500*3200 == NE)
static constexpr int CHUNK = NE / GB;             // 3200 (int4-aligned chunks)

typedef __attribute__((ext_vector_type(8))) short bf16x8;
typedef __attribute__((ext_vector_type(4))) float f32x4;

static __device__ __forceinline__ unsigned short f2bf(float f) {
  unsigned u = __float_as_uint(f);
  unsigned r = (u + 0x7fffu + ((u >> 16) & 1u)) >> 16;  // RNE
  return (unsigned short)r;
}

// ---------------- pass A: per-(bucket,block) histogram (int4 reads) ----------------

__global__ __launch_bounds__(256) void k_hist(const int* __restrict__ row,
                                              int* __restrict__ counts) {
  __shared__ int hist[NB];
  for (int k = threadIdx.x; k < NB; k += 256) hist[k] = 0;
  __syncthreads();
  int g = blockIdx.x;
  int start = g * CHUNK;
  for (int gi = threadIdx.x; gi < CHUNK / 4; gi += 256) {
    int4 r4 = *reinterpret_cast<const int4*>(row + start + gi * 4);
    atomicAdd(&hist[r4.x >> 8], 1);
    atomicAdd(&hist[r4.y >> 8], 1);
    atomicAdd(&hist[r4.z >> 8], 1);
    atomicAdd(&hist[r4.w >> 8], 1);
  }
  __syncthreads();
  for (int k = threadIdx.x; k < NB; k += 256) counts[k * GB + g] = hist[k];
}

// ---------------- scan A: per-bucket exclusive scan of GB block-counts ----------------

__global__ __launch_bounds__(256) void k_scanA(int* __restrict__ counts,
                                               int* __restrict__ totals) {
  __shared__ int s[256];
  __shared__ int carry;
  int k = blockIdx.x;
  if (threadIdx.x == 0) carry = 0;
  __syncthreads();
  for (int base = 0; base < GB; base += 256) {
    int i = base + threadIdx.x;
    int v = (i < GB) ? counts[k * GB + i] : 0;
    s[threadIdx.x] = v;
    __syncthreads();
    for (int off = 1; off < 256; off <<= 1) {
      int t = (threadIdx.x >= off) ? s[threadIdx.x - off] : 0;
      __syncthreads();
      s[threadIdx.x] += t;
      __syncthreads();
    }
    if (i < GB) counts[k * GB + i] = carry + s[threadIdx.x] - v;
    int tile_total = s[255];
    __syncthreads();
    if (threadIdx.x == 0) carry += tile_total;
    __syncthreads();
  }
  if (threadIdx.x == 0) totals[k] = carry;
}

// ---------------- inline totals->bases scan (LDS), shared by bucket/csr ----------------

static __device__ __forceinline__ void scan_totals(const int* __restrict__ totals,
                                                   int* bases_l, int* ss,
                                                   int* carry_p) {
  if (threadIdx.x == 0) *carry_p = 0;
  __syncthreads();
  for (int base = 0; base < NB; base += 256) {
    int i = base + threadIdx.x;
    int v = (i < NB) ? totals[i] : 0;
    ss[threadIdx.x] = v;
    __syncthreads();
    for (int off = 1; off < 256; off <<= 1) {
      int t = (threadIdx.x >= off) ? ss[threadIdx.x - off] : 0;
      __syncthreads();
      ss[threadIdx.x] += t;
      __syncthreads();
    }
    if (i < NB) bases_l[i] = *carry_p + ss[threadIdx.x] - v;
    int tile_total = ss[255];
    __syncthreads();
    if (threadIdx.x == 0) *carry_p += tile_total;
    __syncthreads();
  }
  if (threadIdx.x == 0) bases_l[NB] = *carry_p;
  __syncthreads();
}

// ---------------- pass B: bucket-grouped packed edges (int4 reads) ----------------

__global__ __launch_bounds__(256) void k_bucket(const int* __restrict__ row,
                                                const int* __restrict__ col,
                                                const int* __restrict__ counts,
                                                const int* __restrict__ totals,
                                                unsigned int* __restrict__ packed) {
  __shared__ int cur[NB];
  __shared__ int bases_l[NB + 1];
  __shared__ int ss[256];
  __shared__ int carry;
  scan_totals(totals, bases_l, ss, &carry);

  int g = blockIdx.x;
  for (int k = threadIdx.x; k < NB; k += 256)
    cur[k] = bases_l[k] + counts[k * GB + g];
  __syncthreads();
  int start = g * CHUNK;
  for (int gi = threadIdx.x; gi < CHUNK / 4; gi += 256) {
    int4 r4 = *reinterpret_cast<const int4*>(row + start + gi * 4);
    int4 c4 = *reinterpret_cast<const int4*>(col + start + gi * 4);
    int p0 = atomicAdd(&cur[r4.x >> 8], 1);
    int p1 = atomicAdd(&cur[r4.y >> 8], 1);
    int p2 = atomicAdd(&cur[r4.z >> 8], 1);
    int p3 = atomicAdd(&cur[r4.w >> 8], 1);
    packed[p0] = ((unsigned)(r4.x & 255) << 17) | (unsigned)c4.x;
    packed[p1] = ((unsigned)(r4.y & 255) << 17) | (unsigned)c4.y;
    packed[p2] = ((unsigned)(r4.z & 255) << 17) | (unsigned)c4.z;
    packed[p3] = ((unsigned)(r4.w & 255) << 17) | (unsigned)c4.w;
  }
}

// ---------------- pass C: per-bucket CSR finalize (arrival order) + fused x-cast ----

__global__ __launch_bounds__(256) void k_csr(const unsigned int* __restrict__ packed,
                                             const int* __restrict__ totals,
                                             int* __restrict__ rowptr,
                                             float* __restrict__ dis,
                                             int* __restrict__ csr_col,
                                             const float* __restrict__ x,
                                             unsigned short* __restrict__ xb,
                                             int N, int E) {
  __shared__ int bases_l[NB + 1];
  __shared__ int ss[256];
  __shared__ int carry;
  __shared__ int rh[256];
  __shared__ int cur[256];
  __shared__ float ldis[256];
  scan_totals(totals, bases_l, ss, &carry);

  int b = blockIdx.x;
  int start = bases_l[b];
  int end = bases_l[b + 1];

  rh[threadIdx.x] = 0;
  __syncthreads();
  for (int i = start + threadIdx.x; i < end; i += 256)
    atomicAdd(&rh[packed[i] >> 17], 1);
  __syncthreads();

  int v = rh[threadIdx.x];
  ss[threadIdx.x] = v;
  __syncthreads();
  for (int off = 1; off < 256; off <<= 1) {
    int t = (threadIdx.x >= off) ? ss[threadIdx.x - off] : 0;
    __syncthreads();
    ss[threadIdx.x] += t;
    __syncthreads();
  }
  int exc = ss[threadIdx.x] - v;

  float dv = 1.0f / sqrtf((float)v + 1e-12f);
  ldis[threadIdx.x] = dv;
  int gr = (b << 8) + threadIdx.x;
  if (gr < N) {
    rowptr[gr] = start + exc;
    dis[gr] = dv;
  }
  if (b == NB - 1 && threadIdx.x == 0) rowptr[N] = E;

  cur[threadIdx.x] = exc;
  __syncthreads();
  for (int i = start + threadIdx.x; i < end; i += 256) {
    unsigned p = packed[i];
    int lr = p >> 17;
    int c = (int)(p & 0x1FFFFu);
    int pos = atomicAdd(&cur[lr], 1);
    csr_col[start + pos] = c;
  }

  // fused cast: this bucket's rows of x -> bf16 * dis (coalesced float4 loop)
  int rows = min(256, N - (b << 8));
  if (rows > 0) {
    const float4* xs = reinterpret_cast<const float4*>(x + ((size_t)b << 8) * 32);
    ushort4* xd = reinterpret_cast<ushort4*>(xb + ((size_t)b << 8) * 32);
    for (int i = threadIdx.x; i < rows * 8; i += 256) {
      float ds = ldis[i >> 3];
      float4 vv = xs[i];
      xd[i] = make_ushort4(f2bf(vv.x * ds), f2bf(vv.y * ds),
                           f2bf(vv.z * ds), f2bf(vv.w * ds));
    }
  }
}

// ---------------- bf16 accumulate helper ----------------

template <int SQ>
static __device__ __forceinline__ void acc_bf(float* acc, const uint4* u) {
#pragma unroll
  for (int q = 0; q < SQ; ++q) {
    acc[8 * q + 0] += __uint_as_float(u[q].x << 16);
    acc[8 * q + 1] += __uint_as_float(u[q].x & 0xffff0000u);
    acc[8 * q + 2] += __uint_as_float(u[q].y << 16);
    acc[8 * q + 3] += __uint_as_float(u[q].y & 0xffff0000u);
    acc[8 * q + 4] += __uint_as_float(u[q].z << 16);
    acc[8 * q + 5] += __uint_as_float(u[q].z & 0xffff0000u);
    acc[8 * q + 6] += __uint_as_float(u[q].w << 16);
    acc[8 * q + 7] += __uint_as_float(u[q].w & 0xffff0000u);
  }
}

// ---------------- FUSED layer-1 gather + MFMA double GEMM ----------------
// Block = 64 rows. Phase 1: 4 lanes/row gather xb -> bf16 tile in LDS.
// Phase 2: per-wave 16-row MFMA gemm12 reading B-fragments from the LDS tile.
// s2 rows padded to 64 bf16 = 128B, line-aligned (R17 lesson: 96B rows don't
// reduce line traffic — 2 lines/row either way — and cost idle gather lanes).

__global__ __launch_bounds__(256) void k_g1gemm(
    const uint4* __restrict__ src,            // xb rows = 4 uint4
    const int* __restrict__ rowptr,
    const int* __restrict__ csr_col,
    const float* __restrict__ dis,
    const float* __restrict__ W1,             // [32][48]
    const float* __restrict__ W2,             // [48][48]
    unsigned short* __restrict__ s2,          // [N][64] bf16 (padded)
    int N) {
  __shared__ __align__(16) unsigned short g1l[64][36];
  __shared__ __align__(16) unsigned short hl[4][16][72];

  int rb0 = blockIdx.x * 64;

  // ---- phase 1: gather this block's 64 rows ----
  {
    int lr = threadIdx.x >> 2, gg = threadIdx.x & 3;
    int r = rb0 + lr;
    uint4 pk = make_uint4(0u, 0u, 0u, 0u);
    if (r < N) {
      int j = rowptr[r], end = rowptr[r + 1];
      float acc[8];
#pragma unroll
      for (int q = 0; q < 8; ++q) acc[q] = 0.f;
      for (; j + 4 <= end; j += 4) {
        int c0 = csr_col[j], c1 = csr_col[j + 1];
        int c2 = csr_col[j + 2], c3 = csr_col[j + 3];
        uint4 u0 = src[(size_t)c0 * 4 + gg];
        uint4 u1 = src[(size_t)c1 * 4 + gg];
        uint4 u2 = src[(size_t)c2 * 4 + gg];
        uint4 u3 = src[(size_t)c3 * 4 + gg];
        acc_bf<1>(acc, &u0);
        acc_bf<1>(acc, &u1);
        acc_bf<1>(acc, &u2);
        acc_bf<1>(acc, &u3);
      }
      for (; j < end; ++j) {
        uint4 u0 = src[(size_t)csr_col[j] * 4 + gg];
        acc_bf<1>(acc, &u0);
      }
      float ds = dis[r];
      unsigned* pw = reinterpret_cast<unsigned*>(&pk);
#pragma unroll
      for (int i = 0; i < 4; ++i)
        pw[i] = (unsigned)f2bf(ds * acc[2 * i]) |
                ((unsigned)f2bf(ds * acc[2 * i + 1]) << 16);
    }
    *reinterpret_cast<uint4*>(&g1l[lr][gg * 8]) = pk;
  }
  __syncthreads();

  // ---- phase 2: MFMA gemm12 ----
  int w = threadIdx.x >> 6;   // wave id
  int l = threadIdx.x & 63;
  int c = l & 15;             // node-row slot within tile (MFMA col)
  int g = l >> 4;             // k-group
  int rb = rb0 + w * 16;
  int r = rb + c;
  int rc = min(r, N - 1);

  bf16x8 w1f[3];
#pragma unroll
  for (int t = 0; t < 3; ++t) {
#pragma unroll
    for (int i = 0; i < 8; ++i)
      w1f[t][i] = (short)f2bf(W1[(g * 8 + i) * 48 + 16 * t + c]);
  }
  bf16x8 w2f[3][2];
#pragma unroll
  for (int t = 0; t < 3; ++t) {
#pragma unroll
    for (int s = 0; s < 2; ++s) {
#pragma unroll
      for (int i = 0; i < 8; ++i) {
        int k = s * 32 + g * 8 + i;
        w2f[t][s][i] = (k < 48) ? (short)f2bf(W2[k * 48 + 16 * t + c]) : (short)0;
      }
    }
  }

  bf16x8 bfr = *reinterpret_cast<const bf16x8*>(&g1l[w * 16 + c][g * 8]);
  f32x4 a1[3];
#pragma unroll
  for (int t = 0; t < 3; ++t) {
    a1[t] = f32x4{0.f, 0.f, 0.f, 0.f};
    a1[t] = __builtin_amdgcn_mfma_f32_16x16x32_bf16(w1f[t], bfr, a1[t], 0, 0, 0);
  }

#pragma unroll
  for (int t = 0; t < 3; ++t) {
    int f = 16 * t + 4 * g;
    unsigned p0 = (unsigned)f2bf(fmaxf(a1[t][0], 0.f)) |
                  ((unsigned)f2bf(fmaxf(a1[t][1], 0.f)) << 16);
    unsigned p1 = (unsigned)f2bf(fmaxf(a1[t][2], 0.f)) |
                  ((unsigned)f2bf(fmaxf(a1[t][3], 0.f)) << 16);
    *reinterpret_cast<unsigned*>(&hl[w][c][f]) = p0;
    *reinterpret_cast<unsigned*>(&hl[w][c][f + 2]) = p1;
  }
  *reinterpret_cast<unsigned*>(&hl[w][c][48 + 4 * g]) = 0u;
  *reinterpret_cast<unsigned*>(&hl[w][c][48 + 4 * g + 2]) = 0u;

  f32x4 a2[3];
#pragma unroll
  for (int t = 0; t < 3; ++t) a2[t] = f32x4{0.f, 0.f, 0.f, 0.f};
#pragma unroll
  for (int s = 0; s < 2; ++s) {
    bf16x8 hb = *reinterpret_cast<const bf16x8*>(&hl[w][c][s * 32 + 8 * g]);
#pragma unroll
    for (int t = 0; t < 3; ++t)
      a2[t] = __builtin_amdgcn_mfma_f32_16x16x32_bf16(w2f[t][s], hb, a2[t], 0, 0, 0);
  }

  float ds = dis[rc];
#pragma unroll
  for (int t = 0; t < 3; ++t) {
    int f = 16 * t + 4 * g;
    unsigned p0 = (unsigned)f2bf(ds * a2[t][0]) |
                  ((unsigned)f2bf(ds * a2[t][1]) << 16);
    unsigned p1 = (unsigned)f2bf(ds * a2[t][2]) |
                  ((unsigned)f2bf(ds * a2[t][3]) << 16);
    *reinterpret_cast<unsigned*>(&hl[w][c][f]) = p0;
    *reinterpret_cast<unsigned*>(&hl[w][c][f + 2]) = p1;
  }
#pragma unroll
  for (int h2 = 0; h2 < 2; ++h2) {
    int q = l + 64 * h2;
    int rowq = q >> 3, off = q & 7;
    int rr = rb + rowq;
    if (rr < N) {
      uint4 v = *reinterpret_cast<const uint4*>(&hl[w][rowq][off * 8]);
      *reinterpret_cast<uint4*>(s2 + (size_t)rr * 64 + off * 8) = v;
    }
  }
}

// ---------------- fused layer-2 gather + layer-3 GEMM (bf16 s3 out) ----------------
// Wol stride 68: lane-group g reads bank (4g+c)%32 — conflict-free.

__global__ __launch_bounds__(256) void k_gather_fc(const uint4* __restrict__ src,
                                                   const int* __restrict__ rowptr,
                                                   const int* __restrict__ csr_col,
                                                   const float* __restrict__ dis,
                                                   const float* __restrict__ Wo,
                                                   unsigned short* __restrict__ s3b,
                                                   int N) {
  __shared__ float Wol[8 * 68];
  for (int i = threadIdx.x; i < 8 * 68; i += 256) {
    int gg = i / 68, off = i - gg * 68;
    float v = 0.f;
    if (off < 64) {
      int rowf = gg * 8 + (off >> 3);
      if (rowf < 48) v = Wo[rowf * 8 + (off & 7)];
    }
    Wol[i] = v;
  }
  __syncthreads();

  int t = blockIdx.x * 256 + threadIdx.x;
  int r = t >> 3, g = t & 7;
  if (r >= N) return;
  int j = rowptr[r], end = rowptr[r + 1];

  float acc[8];
#pragma unroll
  for (int q = 0; q < 8; ++q) acc[q] = 0.f;

  for (; j + 4 <= end; j += 4) {
    int c0 = csr_col[j], c1 = csr_col[j + 1], c2 = csr_col[j + 2], c3 = csr_col[j + 3];
    uint4 u0 = src[(size_t)c0 * 8 + g];
    uint4 u1 = src[(size_t)c1 * 8 + g];
    uint4 u2 = src[(size_t)c2 * 8 + g];
    uint4 u3 = src[(size_t)c3 * 8 + g];
    acc_bf<1>(acc, &u0);
    acc_bf<1>(acc, &u1);
    acc_bf<1>(acc, &u2);
    acc_bf<1>(acc, &u3);
  }
  for (; j < end; ++j) {
    uint4 u0 = src[(size_t)csr_col[j] * 8 + g];
    acc_bf<1>(acc, &u0);
  }

  float ds = dis[r];
  float v[8];
#pragma unroll
  for (int q = 0; q < 8; ++q) v[q] = fmaxf(ds * acc[q], 0.f);

  float p[8];
#pragma unroll
  for (int n = 0; n < 8; ++n) p[n] = 0.f;
  const float* wbase = &Wol[g * 68];
#pragma unroll
  for (int q = 0; q < 8; ++q) {
    float4 w0 = *reinterpret_cast<const float4*>(wbase + q * 8);
    float4 w1 = *reinterpret_cast<const float4*>(wbase + q * 8 + 4);
    p[0] = fmaf(v[q], w0.x, p[0]);
    p[1] = fmaf(v[q], w0.y, p[1]);
    p[2] = fmaf(v[q], w0.z, p[2]);
    p[3] = fmaf(v[q], w0.w, p[3]);
    p[4] = fmaf(v[q], w1.x, p[4]);
    p[5] = fmaf(v[q], w1.y, p[5]);
    p[6] = fmaf(v[q], w1.z, p[6]);
    p[7] = fmaf(v[q], w1.w, p[7]);
  }
#pragma unroll
  for (int m = 1; m < 8; m <<= 1) {
#pragma unroll
    for (int n = 0; n < 8; ++n) p[n] += __shfl_xor(p[n], m, 64);
  }
  if (g == 0) {
    uint4 pk;
    unsigned* pw = reinterpret_cast<unsigned*>(&pk);
#pragma unroll
    for (int i = 0; i < 4; ++i)
      pw[i] = (unsigned)f2bf(ds * p[2 * i]) |
              ((unsigned)f2bf(ds * p[2 * i + 1]) << 16);
    *reinterpret_cast<uint4*>(s3b + (size_t)r * 8) = pk;
  }
}

// ---------------- final gather: out[r,:] = dis[r] * sum s3b[col,:] (f32 out) ----------------

__global__ __launch_bounds__(256) void k_gather_s3(const uint4* __restrict__ src,
                                                   const int* __restrict__ rowptr,
                                                   const int* __restrict__ csr_col,
                                                   const float* __restrict__ dis,
                                                   float* __restrict__ out, int N) {
  int r = blockIdx.x * 256 + threadIdx.x;
  if (r >= N) return;
  int j = rowptr[r], end = rowptr[r + 1];

  float acc[8];
#pragma unroll
  for (int q = 0; q < 8; ++q) acc[q] = 0.f;

  for (; j + 4 <= end; j += 4) {
    int c0 = csr_col[j], c1 = csr_col[j + 1], c2 = csr_col[j + 2], c3 = csr_col[j + 3];
    uint4 u0 = src[c0];
    uint4 u1 = src[c1];
    uint4 u2 = src[c2];
    uint4 u3 = src[c3];
    acc_bf<1>(acc, &u0);
    acc_bf<1>(acc, &u1);
    acc_bf<1>(acc, &u2);
    acc_bf<1>(acc, &u3);
  }
  for (; j < end; ++j) {
    uint4 u0 = src[csr_col[j]];
    acc_bf<1>(acc, &u0);
  }

  float ds = dis[r];
  float4* dp = reinterpret_cast<float4*>(out + (size_t)r * 8);
  dp[0] = make_float4(ds * acc[0], ds * acc[1], ds * acc[2], ds * acc[3]);
  dp[1] = make_float4(ds * acc[4], ds * acc[5], ds * acc[6], ds * acc[7]);
}

// ---------------- launch ----------------

extern "C" void kernel_launch(void* const* d_in, const int* in_sizes, int n_in,
                              void* d_out, int out_size, void* d_ws, size_t ws_size,
                              hipStream_t stream) {
  const float* x  = (const float*)d_in[0];
  const int*   ei = (const int*)d_in[1];
  const float* W1 = (const float*)d_in[2];
  const float* W2 = (const float*)d_in[3];
  const float* Wo = (const float*)d_in[4];
  float* out = (float*)d_out;

  const int N = NN, E = NE;
  const int* row = ei;
  const int* col = ei + E;

  // workspace — every buffer on a 128B (32-word) boundary (R15 lesson).
  int*   counts  = (int*)d_ws;                   // 391*500=195500 -> pad 195520
  int*   totals  = counts + 195520;              // 391   -> pad 416
  int*   rowptr  = totals + 416;                 // 100001-> pad 100032
  float* dis     = (float*)(rowptr + 100032);    // 100000
  int*   csr_col = (int*)(dis + 100000);         // 1600000
  float* A1      = (float*)(csr_col + NE);       // 3.2M words, 128B-aligned
  unsigned short* xb  = (unsigned short*)(A1 + 3200000);  // N*32 bf16 (1.6M words)
  unsigned short* s3b = (unsigned short*)(A1 + 4800000);  // N*8 bf16 (0.4M words)
  // aliases (lifetimes disjoint):
  unsigned int*   packed = (unsigned int*)A1;    // CSR build only (1.6M words)
  unsigned short* s2     = (unsigned short*)A1;  // N*64 bf16 rows (3.2M words)

  // ---- CSR build (+fused cast); totals->bases scan inlined in consumers ----
  k_hist<<<GB, 256, 0, stream>>>(row, counts);
  k_scanA<<<NB, 256, 0, stream>>>(counts, totals);
  k_bucket<<<GB, 256, 0, stream>>>(row, col, counts, totals, packed);
  k_csr<<<NB, 256, 0, stream>>>(packed, totals, rowptr, dis, csr_col, x, xb, N, E);

  // ---- fused layer-1 gather + MFMA gemm12: s2 = bf16(dis*(relu((Ā@xb)@W1)@W2)) ----
  k_g1gemm<<<(N + 63) / 64, 256, 0, stream>>>(
      (const uint4*)xb, rowptr, csr_col, dis, W1, W2, s2, N);

  // ---- fused layer-2 gather + layer-3 GEMM: s3b = bf16(dis*(relu(dis*(Ā@s2))@Wo)) ----
  k_gather_fc<<<(N * 8 + 255) / 256, 256, 0, stream>>>(
      (const uint4*)s2, rowptr, csr_col, dis, Wo, s3b, N);

  // ---- final gather: out = dis⊙(Ā@s3b) ----
  k_gather_s3<<<(N + 255) / 256, 256, 0, stream>>>(
      (const uint4*)s3b, rowptr, csr_col, dis, out, N);
}

// Round 19
// 124.740 us; speedup vs baseline: 1.0358x; 1.0280x over previous
//
#include <hip/hip_runtime.h>
#include <hip/hip_bf16.h>
#include <cstdint>
#include <cstddef>

static constexpr int NN = 100000;   // nodes
static constexpr int NE = 1600000;  // edges
static constexpr int NB = 391;      // buckets of 256 rows
static constexpr int GB = 250;      // blocks in hist/bucket passes (250*6400 == NE)
static constexpr int CHUNK = NE / GB;             // 6400 (int4-aligned chunks)

typedef __attribute__((ext_vector_type(8))) short bf16x8;
typedef __attribute__((ext_vector_type(4))) float f32x4;

static __device__ __forceinline__ unsigned short f2bf(float f) {
  unsigned u = __float_as_uint(f);
  unsigned r = (u + 0x7fffu + ((u >> 16) & 1u)) >> 16;  // RNE
  return (unsigned short)r;
}

// ---------------- pass A: per-(bucket,block) histogram (int4 reads) ----------------

__global__ __launch_bounds__(256) void k_hist(const int* __restrict__ row,
                                              int* __restrict__ counts) {
  __shared__ int hist[NB];
  for (int k = threadIdx.x; k < NB; k += 256) hist[k] = 0;
  __syncthreads();
  int g = blockIdx.x;
  int start = g * CHUNK;
  for (int gi = threadIdx.x; gi < CHUNK / 4; gi += 256) {
    int4 r4 = *reinterpret_cast<const int4*>(row + start + gi * 4);
    atomicAdd(&hist[r4.x >> 8], 1);
    atomicAdd(&hist[r4.y >> 8], 1);
    atomicAdd(&hist[r4.z >> 8], 1);
    atomicAdd(&hist[r4.w >> 8], 1);
  }
  __syncthreads();
  for (int k = threadIdx.x; k < NB; k += 256) counts[k * GB + g] = hist[k];
}

// ---------------- scan A: per-bucket exclusive scan of 250 block-counts ----------------

__global__ __launch_bounds__(256) void k_scanA(int* __restrict__ counts,
                                               int* __restrict__ totals) {
  __shared__ int s[256];
  int k = blockIdx.x;
  int i = threadIdx.x;
  int v = (i < GB) ? counts[k * GB + i] : 0;
  s[i] = v;
  __syncthreads();
  for (int off = 1; off < 256; off <<= 1) {
    int t = (i >= off) ? s[i - off] : 0;
    __syncthreads();
    s[i] += t;
    __syncthreads();
  }
  if (i < GB) counts[k * GB + i] = s[i] - v;
  if (i == 255) totals[k] = s[255];
}

// ---------------- inline totals->bases scan (LDS), shared by bucket/csr ----------------

static __device__ __forceinline__ void scan_totals(const int* __restrict__ totals,
                                                   int* bases_l, int* ss,
                                                   int* carry_p) {
  if (threadIdx.x == 0) *carry_p = 0;
  __syncthreads();
  for (int base = 0; base < NB; base += 256) {
    int i = base + threadIdx.x;
    int v = (i < NB) ? totals[i] : 0;
    ss[threadIdx.x] = v;
    __syncthreads();
    for (int off = 1; off < 256; off <<= 1) {
      int t = (threadIdx.x >= off) ? ss[threadIdx.x - off] : 0;
      __syncthreads();
      ss[threadIdx.x] += t;
      __syncthreads();
    }
    if (i < NB) bases_l[i] = *carry_p + ss[threadIdx.x] - v;
    int tile_total = ss[255];
    __syncthreads();
    if (threadIdx.x == 0) *carry_p += tile_total;
    __syncthreads();
  }
  if (threadIdx.x == 0) bases_l[NB] = *carry_p;
  __syncthreads();
}

// ---------------- pass B: bucket-grouped packed edges (int4 reads) ----------------

__global__ __launch_bounds__(256) void k_bucket(const int* __restrict__ row,
                                                const int* __restrict__ col,
                                                const int* __restrict__ counts,
                                                const int* __restrict__ totals,
                                                unsigned int* __restrict__ packed) {
  __shared__ int cur[NB];
  __shared__ int bases_l[NB + 1];
  __shared__ int ss[256];
  __shared__ int carry;
  scan_totals(totals, bases_l, ss, &carry);

  int g = blockIdx.x;
  for (int k = threadIdx.x; k < NB; k += 256)
    cur[k] = bases_l[k] + counts[k * GB + g];
  __syncthreads();
  int start = g * CHUNK;
  for (int gi = threadIdx.x; gi < CHUNK / 4; gi += 256) {
    int4 r4 = *reinterpret_cast<const int4*>(row + start + gi * 4);
    int4 c4 = *reinterpret_cast<const int4*>(col + start + gi * 4);
    int p0 = atomicAdd(&cur[r4.x >> 8], 1);
    int p1 = atomicAdd(&cur[r4.y >> 8], 1);
    int p2 = atomicAdd(&cur[r4.z >> 8], 1);
    int p3 = atomicAdd(&cur[r4.w >> 8], 1);
    packed[p0] = ((unsigned)(r4.x & 255) << 17) | (unsigned)c4.x;
    packed[p1] = ((unsigned)(r4.y & 255) << 17) | (unsigned)c4.y;
    packed[p2] = ((unsigned)(r4.z & 255) << 17) | (unsigned)c4.z;
    packed[p3] = ((unsigned)(r4.w & 255) << 17) | (unsigned)c4.w;
  }
}

// ---------------- pass C: per-bucket CSR finalize (arrival order) + fused x-cast ----

__global__ __launch_bounds__(256) void k_csr(const unsigned int* __restrict__ packed,
                                             const int* __restrict__ totals,
                                             int* __restrict__ rowptr,
                                             float* __restrict__ dis,
                                             int* __restrict__ csr_col,
                                             const float* __restrict__ x,
                                             unsigned short* __restrict__ xb,
                                             int N, int E) {
  __shared__ int bases_l[NB + 1];
  __shared__ int ss[256];
  __shared__ int carry;
  __shared__ int rh[256];
  __shared__ int cur[256];
  __shared__ float ldis[256];
  scan_totals(totals, bases_l, ss, &carry);

  int b = blockIdx.x;
  int start = bases_l[b];
  int end = bases_l[b + 1];

  rh[threadIdx.x] = 0;
  __syncthreads();
  for (int i = start + threadIdx.x; i < end; i += 256)
    atomicAdd(&rh[packed[i] >> 17], 1);
  __syncthreads();

  int v = rh[threadIdx.x];
  ss[threadIdx.x] = v;
  __syncthreads();
  for (int off = 1; off < 256; off <<= 1) {
    int t = (threadIdx.x >= off) ? ss[threadIdx.x - off] : 0;
    __syncthreads();
    ss[threadIdx.x] += t;
    __syncthreads();
  }
  int exc = ss[threadIdx.x] - v;

  float dv = 1.0f / sqrtf((float)v + 1e-12f);
  ldis[threadIdx.x] = dv;
  int gr = (b << 8) + threadIdx.x;
  if (gr < N) {
    rowptr[gr] = start + exc;
    dis[gr] = dv;
  }
  if (b == NB - 1 && threadIdx.x == 0) rowptr[N] = E;

  cur[threadIdx.x] = exc;
  __syncthreads();
  for (int i = start + threadIdx.x; i < end; i += 256) {
    unsigned p = packed[i];
    int lr = p >> 17;
    int c = (int)(p & 0x1FFFFu);
    int pos = atomicAdd(&cur[lr], 1);
    csr_col[start + pos] = c;
  }

  // fused cast: this bucket's rows of x -> bf16 * dis (coalesced float4 loop)
  int rows = min(256, N - (b << 8));
  if (rows > 0) {
    const float4* xs = reinterpret_cast<const float4*>(x + ((size_t)b << 8) * 32);
    ushort4* xd = reinterpret_cast<ushort4*>(xb + ((size_t)b << 8) * 32);
    for (int i = threadIdx.x; i < rows * 8; i += 256) {
      float ds = ldis[i >> 3];
      float4 vv = xs[i];
      xd[i] = make_ushort4(f2bf(vv.x * ds), f2bf(vv.y * ds),
                           f2bf(vv.z * ds), f2bf(vv.w * ds));
    }
  }
}

// ---------------- bf16 accumulate helper ----------------

template <int SQ>
static __device__ __forceinline__ void acc_bf(float* acc, const uint4* u) {
#pragma unroll
  for (int q = 0; q < SQ; ++q) {
    acc[8 * q + 0] += __uint_as_float(u[q].x << 16);
    acc[8 * q + 1] += __uint_as_float(u[q].x & 0xffff0000u);
    acc[8 * q + 2] += __uint_as_float(u[q].y << 16);
    acc[8 * q + 3] += __uint_as_float(u[q].y & 0xffff0000u);
    acc[8 * q + 4] += __uint_as_float(u[q].z << 16);
    acc[8 * q + 5] += __uint_as_float(u[q].z & 0xffff0000u);
    acc[8 * q + 6] += __uint_as_float(u[q].w << 16);
    acc[8 * q + 7] += __uint_as_float(u[q].w & 0xffff0000u);
  }
}

// ---------------- FUSED layer-1 gather + MFMA double GEMM ----------------
// Block = 64 rows. Phase 1: 4 lanes/row gather xb -> bf16 tile in LDS.
// Phase 2: per-wave 16-row MFMA gemm12 reading B-fragments from the LDS tile.
// s2 rows padded to 64 bf16 = 128B, line-aligned.

__global__ __launch_bounds__(256) void k_g1gemm(
    const uint4* __restrict__ src,            // xb rows = 4 uint4
    const int* __restrict__ rowptr,
    const int* __restrict__ csr_col,
    const float* __restrict__ dis,
    const float* __restrict__ W1,             // [32][48]
    const float* __restrict__ W2,             // [48][48]
    unsigned short* __restrict__ s2,          // [N][64] bf16 (padded)
    int N) {
  __shared__ __align__(16) unsigned short g1l[64][36];
  __shared__ __align__(16) unsigned short hl[4][16][72];

  int rb0 = blockIdx.x * 64;

  // ---- phase 1: gather this block's 64 rows ----
  {
    int lr = threadIdx.x >> 2, gg = threadIdx.x & 3;
    int r = rb0 + lr;
    uint4 pk = make_uint4(0u, 0u, 0u, 0u);
    if (r < N) {
      int j = rowptr[r], end = rowptr[r + 1];
      float acc[8];
#pragma unroll
      for (int q = 0; q < 8; ++q) acc[q] = 0.f;
      for (; j + 4 <= end; j += 4) {
        int c0 = csr_col[j], c1 = csr_col[j + 1];
        int c2 = csr_col[j + 2], c3 = csr_col[j + 3];
        uint4 u0 = src[(size_t)c0 * 4 + gg];
        uint4 u1 = src[(size_t)c1 * 4 + gg];
        uint4 u2 = src[(size_t)c2 * 4 + gg];
        uint4 u3 = src[(size_t)c3 * 4 + gg];
        acc_bf<1>(acc, &u0);
        acc_bf<1>(acc, &u1);
        acc_bf<1>(acc, &u2);
        acc_bf<1>(acc, &u3);
      }
      for (; j < end; ++j) {
        uint4 u0 = src[(size_t)csr_col[j] * 4 + gg];
        acc_bf<1>(acc, &u0);
      }
      float ds = dis[r];
      unsigned* pw = reinterpret_cast<unsigned*>(&pk);
#pragma unroll
      for (int i = 0; i < 4; ++i)
        pw[i] = (unsigned)f2bf(ds * acc[2 * i]) |
                ((unsigned)f2bf(ds * acc[2 * i + 1]) << 16);
    }
    *reinterpret_cast<uint4*>(&g1l[lr][gg * 8]) = pk;
  }
  __syncthreads();

  // ---- phase 2: MFMA gemm12 ----
  int w = threadIdx.x >> 6;   // wave id
  int l = threadIdx.x & 63;
  int c = l & 15;             // node-row slot within tile (MFMA col)
  int g = l >> 4;             // k-group
  int rb = rb0 + w * 16;
  int r = rb + c;
  int rc = min(r, N - 1);

  bf16x8 w1f[3];
#pragma unroll
  for (int t = 0; t < 3; ++t) {
#pragma unroll
    for (int i = 0; i < 8; ++i)
      w1f[t][i] = (short)f2bf(W1[(g * 8 + i) * 48 + 16 * t + c]);
  }
  bf16x8 w2f[3][2];
#pragma unroll
  for (int t = 0; t < 3; ++t) {
#pragma unroll
    for (int s = 0; s < 2; ++s) {
#pragma unroll
      for (int i = 0; i < 8; ++i) {
        int k = s * 32 + g * 8 + i;
        w2f[t][s][i] = (k < 48) ? (short)f2bf(W2[k * 48 + 16 * t + c]) : (short)0;
      }
    }
  }

  bf16x8 bfr = *reinterpret_cast<const bf16x8*>(&g1l[w * 16 + c][g * 8]);
  f32x4 a1[3];
#pragma unroll
  for (int t = 0; t < 3; ++t) {
    a1[t] = f32x4{0.f, 0.f, 0.f, 0.f};
    a1[t] = __builtin_amdgcn_mfma_f32_16x16x32_bf16(w1f[t], bfr, a1[t], 0, 0, 0);
  }

#pragma unroll
  for (int t = 0; t < 3; ++t) {
    int f = 16 * t + 4 * g;
    unsigned p0 = (unsigned)f2bf(fmaxf(a1[t][0], 0.f)) |
                  ((unsigned)f2bf(fmaxf(a1[t][1], 0.f)) << 16);
    unsigned p1 = (unsigned)f2bf(fmaxf(a1[t][2], 0.f)) |
                  ((unsigned)f2bf(fmaxf(a1[t][3], 0.f)) << 16);
    *reinterpret_cast<unsigned*>(&hl[w][c][f]) = p0;
    *reinterpret_cast<unsigned*>(&hl[w][c][f + 2]) = p1;
  }
  *reinterpret_cast<unsigned*>(&hl[w][c][48 + 4 * g]) = 0u;
  *reinterpret_cast<unsigned*>(&hl[w][c][48 + 4 * g + 2]) = 0u;

  f32x4 a2[3];
#pragma unroll
  for (int t = 0; t < 3; ++t) a2[t] = f32x4{0.f, 0.f, 0.f, 0.f};
#pragma unroll
  for (int s = 0; s < 2; ++s) {
    bf16x8 hb = *reinterpret_cast<const bf16x8*>(&hl[w][c][s * 32 + 8 * g]);
#pragma unroll
    for (int t = 0; t < 3; ++t)
      a2[t] = __builtin_amdgcn_mfma_f32_16x16x32_bf16(w2f[t][s], hb, a2[t], 0, 0, 0);
  }

  float ds = dis[rc];
#pragma unroll
  for (int t = 0; t < 3; ++t) {
    int f = 16 * t + 4 * g;
    unsigned p0 = (unsigned)f2bf(ds * a2[t][0]) |
                  ((unsigned)f2bf(ds * a2[t][1]) << 16);
    unsigned p1 = (unsigned)f2bf(ds * a2[t][2]) |
                  ((unsigned)f2bf(ds * a2[t][3]) << 16);
    *reinterpret_cast<unsigned*>(&hl[w][c][f]) = p0;
    *reinterpret_cast<unsigned*>(&hl[w][c][f + 2]) = p1;
  }
#pragma unroll
  for (int h2 = 0; h2 < 2; ++h2) {
    int q = l + 64 * h2;
    int rowq = q >> 3, off = q & 7;
    int rr = rb + rowq;
    if (rr < N) {
      uint4 v = *reinterpret_cast<const uint4*>(&hl[w][rowq][off * 8]);
      *reinterpret_cast<uint4*>(s2 + (size_t)rr * 64 + off * 8) = v;
    }
  }
}

// ---------------- fused layer-2 gather + layer-3 GEMM (bf16 s3 out) ----------------
// Wol stride 68: lane-group g reads bank (4g+c)%32 — conflict-free.

__global__ __launch_bounds__(256) void k_gather_fc(const uint4* __restrict__ src,
                                                   const int* __restrict__ rowptr,
                                                   const int* __restrict__ csr_col,
                                                   const float* __restrict__ dis,
                                                   const float* __restrict__ Wo,
                                                   unsigned short* __restrict__ s3b,
                                                   int N) {
  __shared__ float Wol[8 * 68];
  for (int i = threadIdx.x; i < 8 * 68; i += 256) {
    int gg = i / 68, off = i - gg * 68;
    float v = 0.f;
    if (off < 64) {
      int rowf = gg * 8 + (off >> 3);
      if (rowf < 48) v = Wo[rowf * 8 + (off & 7)];
    }
    Wol[i] = v;
  }
  __syncthreads();

  int t = blockIdx.x * 256 + threadIdx.x;
  int r = t >> 3, g = t & 7;
  if (r >= N) return;
  int j = rowptr[r], end = rowptr[r + 1];

  float acc[8];
#pragma unroll
  for (int q = 0; q < 8; ++q) acc[q] = 0.f;

  for (; j + 4 <= end; j += 4) {
    int c0 = csr_col[j], c1 = csr_col[j + 1], c2 = csr_col[j + 2], c3 = csr_col[j + 3];
    uint4 u0 = src[(size_t)c0 * 8 + g];
    uint4 u1 = src[(size_t)c1 * 8 + g];
    uint4 u2 = src[(size_t)c2 * 8 + g];
    uint4 u3 = src[(size_t)c3 * 8 + g];
    acc_bf<1>(acc, &u0);
    acc_bf<1>(acc, &u1);
    acc_bf<1>(acc, &u2);
    acc_bf<1>(acc, &u3);
  }
  for (; j < end; ++j) {
    uint4 u0 = src[(size_t)csr_col[j] * 8 + g];
    acc_bf<1>(acc, &u0);
  }

  float ds = dis[r];
  float v[8];
#pragma unroll
  for (int q = 0; q < 8; ++q) v[q] = fmaxf(ds * acc[q], 0.f);

  float p[8];
#pragma unroll
  for (int n = 0; n < 8; ++n) p[n] = 0.f;
  const float* wbase = &Wol[g * 68];
#pragma unroll
  for (int q = 0; q < 8; ++q) {
    float4 w0 = *reinterpret_cast<const float4*>(wbase + q * 8);
    float4 w1 = *reinterpret_cast<const float4*>(wbase + q * 8 + 4);
    p[0] = fmaf(v[q], w0.x, p[0]);
    p[1] = fmaf(v[q], w0.y, p[1]);
    p[2] = fmaf(v[q], w0.z, p[2]);
    p[3] = fmaf(v[q], w0.w, p[3]);
    p[4] = fmaf(v[q], w1.x, p[4]);
    p[5] = fmaf(v[q], w1.y, p[5]);
    p[6] = fmaf(v[q], w1.z, p[6]);
    p[7] = fmaf(v[q], w1.w, p[7]);
  }
#pragma unroll
  for (int m = 1; m < 8; m <<= 1) {
#pragma unroll
    for (int n = 0; n < 8; ++n) p[n] += __shfl_xor(p[n], m, 64);
  }
  if (g == 0) {
    uint4 pk;
    unsigned* pw = reinterpret_cast<unsigned*>(&pk);
#pragma unroll
    for (int i = 0; i < 4; ++i)
      pw[i] = (unsigned)f2bf(ds * p[2 * i]) |
              ((unsigned)f2bf(ds * p[2 * i + 1]) << 16);
    *reinterpret_cast<uint4*>(s3b + (size_t)r * 8) = pk;
  }
}

// ---------------- final gather: out[r,:] = dis[r] * sum s3b[col,:] (f32 out) ----------------

__global__ __launch_bounds__(256) void k_gather_s3(const uint4* __restrict__ src,
                                                   const int* __restrict__ rowptr,
                                                   const int* __restrict__ csr_col,
                                                   const float* __restrict__ dis,
                                                   float* __restrict__ out, int N) {
  int r = blockIdx.x * 256 + threadIdx.x;
  if (r >= N) return;
  int j = rowptr[r], end = rowptr[r + 1];

  float acc[8];
#pragma unroll
  for (int q = 0; q < 8; ++q) acc[q] = 0.f;

  for (; j + 4 <= end; j += 4) {
    int c0 = csr_col[j], c1 = csr_col[j + 1], c2 = csr_col[j + 2], c3 = csr_col[j + 3];
    uint4 u0 = src[c0];
    uint4 u1 = src[c1];
    uint4 u2 = src[c2];
    uint4 u3 = src[c3];
    acc_bf<1>(acc, &u0);
    acc_bf<1>(acc, &u1);
    acc_bf<1>(acc, &u2);
    acc_bf<1>(acc, &u3);
  }
  for (; j < end; ++j) {
    uint4 u0 = src[csr_col[j]];
    acc_bf<1>(acc, &u0);
  }

  float ds = dis[r];
  float4* dp = reinterpret_cast<float4*>(out + (size_t)r * 8);
  dp[0] = make_float4(ds * acc[0], ds * acc[1], ds * acc[2], ds * acc[3]);
  dp[1] = make_float4(ds * acc[4], ds * acc[5], ds * acc[6], ds * acc[7]);
}

// ---------------- launch ----------------

extern "C" void kernel_launch(void* const* d_in, const int* in_sizes, int n_in,
                              void* d_out, int out_size, void* d_ws, size_t ws_size,
                              hipStream_t stream) {
  const float* x  = (const float*)d_in[0];
  const int*   ei = (const int*)d_in[1];
  const float* W1 = (const float*)d_in[2];
  const float* W2 = (const float*)d_in[3];
  const float* Wo = (const float*)d_in[4];
  float* out = (float*)d_out;

  const int N = NN, E = NE;
  const int* row = ei;
  const int* col = ei + E;

  // workspace — every buffer on a 128B (32-word) boundary (R15 lesson).
  int*   counts  = (int*)d_ws;                   // 97750 -> pad 97760
  int*   totals  = counts + 97760;               // 391   -> pad 416
  int*   rowptr  = totals + 416;                 // 100001-> pad 100032
  float* dis     = (float*)(rowptr + 100032);    // 100000
  int*   csr_col = (int*)(dis + 100000);         // 1600000
  float* A1      = (float*)(csr_col + NE);       // 3.2M words, 128B-aligned
  unsigned short* xb  = (unsigned short*)(A1 + 3200000);  // N*32 bf16 (1.6M words)
  unsigned short* s3b = (unsigned short*)(A1 + 4800000);  // N*8 bf16 (0.4M words)
  // aliases (lifetimes disjoint):
  unsigned int*   packed = (unsigned int*)A1;    // CSR build only (1.6M words)
  unsigned short* s2     = (unsigned short*)A1;  // N*64 bf16 rows (3.2M words)

  // ---- CSR build (+fused cast); totals->bases scan inlined in consumers ----
  k_hist<<<GB, 256, 0, stream>>>(row, counts);
  k_scanA<<<NB, 256, 0, stream>>>(counts, totals);
  k_bucket<<<GB, 256, 0, stream>>>(row, col, counts, totals, packed);
  k_csr<<<NB, 256, 0, stream>>>(packed, totals, rowptr, dis, csr_col, x, xb, N, E);

  // ---- fused layer-1 gather + MFMA gemm12: s2 = bf16(dis*(relu((Ā@xb)@W1)@W2)) ----
  k_g1gemm<<<(N + 63) / 64, 256, 0, stream>>>(
      (const uint4*)xb, rowptr, csr_col, dis, W1, W2, s2, N);

  // ---- fused layer-2 gather + layer-3 GEMM: s3b = bf16(dis*(relu(dis*(Ā@s2))@Wo)) ----
  k_gather_fc<<<(N * 8 + 255) / 256, 256, 0, stream>>>(
      (const uint4*)s2, rowptr, csr_col, dis, Wo, s3b, N);

  // ---- final gather: out = dis⊙(Ā@s3b) ----
  k_gather_s3<<<(N + 255) / 256, 256, 0, stream>>>(
      (const uint4*)s3b, rowptr, csr_col, dis, out, N);
}